// Round 5
// baseline (252.058 us; speedup 1.0000x reference)
//
#include <hip/hip_runtime.h>
#include <hip/hip_bf16.h>
#include <stdint.h>

#define S_LEN 2048
#define HID 2880
#define NH 64
#define NKV 8
#define HD 64
#define NQ (NH * HD)     // 4096
#define NKVD (NKV * HD)  // 512
#define SCALE 0.125f

typedef unsigned short u16;
typedef __attribute__((ext_vector_type(8))) short short8;
typedef __attribute__((ext_vector_type(4))) float floatx4;

__device__ __forceinline__ u16 f2bf(float f) {
  union { float f; unsigned u; } x; x.f = f;
  unsigned r = x.u + 0x7fffu + ((x.u >> 16) & 1u);
  return (u16)(r >> 16);
}
__device__ __forceinline__ float bf2f(u16 u) {
  union { unsigned u; float f; } x; x.u = ((unsigned)u) << 16;
  return x.f;
}

// bijective XCD-aware block swizzle (m204): contiguous chunk per XCD
__device__ __forceinline__ int xcd_swz(int orig, int nwg) {
  int q = nwg >> 3, r = nwg & 7, xcd = orig & 7, lid = orig >> 3;
  return (xcd < r ? xcd * (q + 1) : r * (q + 1) + (xcd - r) * q) + lid;
}

// global -> LDS async copy, 16B per lane. LDS dest is wave-uniform base;
// HW writes lane i at base + i*16.
__device__ __forceinline__ void gl2lds16(const void* g, void* l) {
  __builtin_amdgcn_global_load_lds(
      (__attribute__((address_space(1))) unsigned int*)(uintptr_t)g,
      (__attribute__((address_space(3))) unsigned int*)(unsigned int)(uintptr_t)l,
      16, 0, 0);
}

// ---------------- convert f32 -> bf16 ----------------
__global__ void k_convert(const float* __restrict__ in, u16* __restrict__ out, int n4) {
  int i = blockIdx.x * blockDim.x + threadIdx.x;
  if (i >= n4) return;
  float4 v = *((const float4*)in + i);
  ushort4 o;
  o.x = f2bf(v.x); o.y = f2bf(v.y); o.z = f2bf(v.z); o.w = f2bf(v.w);
  *(ushort4*)(out + (size_t)i * 4) = o;
}

// ---------------- transpose f32[R][C] -> bf16[C][R] ----------------
__global__ void k_transpose(const float* __restrict__ in, u16* __restrict__ out, int R, int C) {
  __shared__ float tile[32][33];
  int bx = blockIdx.x * 32, by = blockIdx.y * 32;
  int tx = threadIdx.x, ty = threadIdx.y;
#pragma unroll
  for (int i = 0; i < 4; ++i)
    tile[ty + i * 8][tx] = in[(long)(by + ty + i * 8) * C + bx + tx];
  __syncthreads();
#pragma unroll
  for (int i = 0; i < 4; ++i)
    out[(long)(bx + ty + i * 8) * R + by + tx] = f2bf(tile[tx][ty + i * 8]);
}

// ---------------- 128x128 bf16 MFMA GEMM core ----------------
// 4-buffer ring, counted vmcnt(8) steady state, raw s_barrier: loads for tiles
// t+1..t+3 stay in flight across barriers (~3 K-steps of latency coverage,
// matching L3-hit latency). Requires nk >= 3 (always true here: nk=90 or 128).
// Race safety: wave waits its own vmcnt so tile t is resident at barrier t;
// STAGE(t+3) overwrites buf((t-1)&3), legal since all waves finished
// compute(t-1) before arriving at barrier t.
__device__ __forceinline__ void gemm_tile(const u16* __restrict__ Abase, int lda,
                                          const u16* __restrict__ Bbase, int ldb,
                                          int kloop, floatx4 acc[4][4]) {
  __shared__ __align__(16) u16 As[4][128][32];
  __shared__ __align__(16) u16 Bs[4][128][32];
  const int t = threadIdx.x;
  const int w = t >> 6, l = t & 63;
  const int srow = w * 16 + (l >> 2);   // staging row within 64-row pass
  const int scol = (l & 3) * 8;         // staging col (bf16 elems)
  const int wr = (w >> 1) * 64, wc = (w & 1) * 64;
  const int fr = l & 15, fk8 = (l >> 4) * 8;
  floatx4 zero = {0.f, 0.f, 0.f, 0.f};
#pragma unroll
  for (int i = 0; i < 4; ++i)
#pragma unroll
    for (int j = 0; j < 4; ++j) acc[i][j] = zero;

  const u16* Ar0 = Abase + (long)srow * lda + scol;
  const u16* Ar1 = Abase + (long)(64 + srow) * lda + scol;
  const u16* Br0 = Bbase + (long)srow * ldb + scol;
  const u16* Br1 = Bbase + (long)(64 + srow) * ldb + scol;

#define STAGE(buf, kt) do {                              \
    long ko_ = (long)(kt) * 32;                          \
    gl2lds16(Ar0 + ko_, &As[buf][w * 16][0]);            \
    gl2lds16(Ar1 + ko_, &As[buf][64 + w * 16][0]);       \
    gl2lds16(Br0 + ko_, &Bs[buf][w * 16][0]);            \
    gl2lds16(Br1 + ko_, &Bs[buf][64 + w * 16][0]);       \
  } while (0)

  const int nk = kloop >> 5;            // nk >= 3 assumed
  STAGE(0, 0);
  STAGE(1, 1);
  STAGE(2, 2);
  for (int kt = 0; kt < nk; ++kt) {
    if (kt + 2 < nk)      { asm volatile("s_waitcnt vmcnt(8)" ::: "memory"); }
    else if (kt + 1 < nk) { asm volatile("s_waitcnt vmcnt(4)" ::: "memory"); }
    else                  { asm volatile("s_waitcnt vmcnt(0)" ::: "memory"); }
    asm volatile("s_barrier" ::: "memory");   // tile `cur` resident for ALL waves
    if (kt + 3 < nk) STAGE((kt + 3) & 3, kt + 3);
    const int cur = kt & 3;
    short8 af[4], bf8[4];
#pragma unroll
    for (int i = 0; i < 4; ++i) af[i] = *(const short8*)&As[cur][wr + i * 16 + fr][fk8];
#pragma unroll
    for (int j = 0; j < 4; ++j) bf8[j] = *(const short8*)&Bs[cur][wc + j * 16 + fr][fk8];
#pragma unroll
    for (int i = 0; i < 4; ++i)
#pragma unroll
      for (int j = 0; j < 4; ++j)
        acc[i][j] = __builtin_amdgcn_mfma_f32_16x16x32_bf16(af[i], bf8[j], acc[i][j], 0, 0, 0);
  }
#undef STAGE
}

// ---------------- QKV GEMM + bias + fused RoPE, scatter epilogue ----------------
// q -> qbuf[h][s][d] (rope'd), k -> kbuf[kvh][s][d] (rope'd), v -> vtbuf[kvh][d][s]
// Block mapping: bm-FASTEST (sw&15) so each XCD chunk (80 blocks = 5 bn x 16 bm)
// touches only 5 B-panels (3.7 MB, L2-resident) + the shared A (11.8 MB) --
// per-XCD compulsory ~15.5 MB vs 31 MB with bn-fastest (measured 226 MB FETCH).
__global__ __launch_bounds__(256) void k_gemm_qkv(
    const u16* __restrict__ hsb, const u16* __restrict__ wqt,
    const u16* __restrict__ wkt, const u16* __restrict__ wvt,
    const float* __restrict__ bq, const float* __restrict__ bk, const float* __restrict__ bv,
    const float* __restrict__ cosb, const float* __restrict__ sinb,
    u16* __restrict__ qbuf, u16* __restrict__ kbuf, u16* __restrict__ vtbuf) {
  int sw = xcd_swz(blockIdx.x, gridDim.x);       // 640 blocks
  int bm = (sw & 15) * 128, bn = (sw >> 4) * 128;
  const u16* Bt; const float* bias;
  if (bn < NQ)              { Bt = wqt + (long)bn * HID;               bias = bq + bn; }
  else if (bn < NQ + NKVD)  { Bt = wkt + (long)(bn - NQ) * HID;        bias = bk + (bn - NQ); }
  else                      { Bt = wvt + (long)(bn - NQ - NKVD) * HID; bias = bv + (bn - NQ - NKVD); }
  floatx4 acc[4][4];
  gemm_tile(hsb + (long)bm * HID, HID, Bt, HID, HID, acc);
  int t = threadIdx.x, w = t >> 6, l = t & 63;
  int wr = (w >> 1) * 64, wc = (w & 1) * 64, fr = l & 15, fq = (l >> 4) * 4;
  if (bn < NQ + NKVD) {
    // q/k path with fused RoPE. Head window = [bn+wc, bn+wc+64), 64-aligned.
    int ng0 = bn + wc;                         // head base (global col)
    u16* hbase;
    if (ng0 < NQ) hbase = qbuf + (long)(ng0 >> 6) * S_LEN * HD;
    else          hbase = kbuf + (long)((ng0 - NQ) >> 6) * S_LEN * HD;
#pragma unroll
    for (int i = 0; i < 4; ++i)
#pragma unroll
      for (int r = 0; r < 4; ++r) {
        int srow = bm + wr + i * 16 + fq + r;
        const float* crow = cosb + (long)srow * HD;
        const float* srw  = sinb + (long)srow * HD;
#pragma unroll
        for (int j = 0; j < 2; ++j) {
          int dlo = j * 16 + fr;               // in [0,32)
          float c  = crow[dlo];
          float si = srw[dlo];
          float xl = acc[i][j][r]     + bias[wc + j * 16 + fr];
          float xh = acc[i][j + 2][r] + bias[wc + (j + 2) * 16 + fr];
          u16 nl = f2bf(xl * c - xh * si);
          u16 nh = f2bf(xh * c + xl * si);
          hbase[(long)srow * HD + dlo]      = nl;
          hbase[(long)srow * HD + dlo + 32] = nh;
        }
      }
  } else {
    // v path: transposed scatter vtbuf[kvh][d][s]
#pragma unroll
    for (int i = 0; i < 4; ++i)
#pragma unroll
      for (int j = 0; j < 4; ++j) {
        int ncol = wc + j * 16 + fr;
        int n3 = bn + ncol - NQ - NKVD;
        float bsv = bias[ncol];
#pragma unroll
        for (int r = 0; r < 4; ++r) {
          int srow = bm + wr + i * 16 + fq + r;
          vtbuf[(long)(n3 >> 6) * HD * S_LEN + (long)(n3 & 63) * S_LEN + srow] =
              f2bf(acc[i][j][r] + bsv);
        }
      }
  }
}

// ---------------- sliding-window GQA attention with sinks ----------------
// grid (S/64, NH); block 256 (4 waves x 16 queries). Window keys staged: 192.
__global__ __launch_bounds__(256) void k_attn(
    const u16* __restrict__ qb, const u16* __restrict__ kb, const u16* __restrict__ vtb,
    const float* __restrict__ sinks, u16* __restrict__ ao) {
  __shared__ __align__(16) u16 Kl[192][72];   // 27648 B; reused as P[4][16][200] after QK
  __shared__ __align__(16) u16 Vl[64][200];   // V transposed: [d][key]
  int t = threadIdx.x;
  int h = blockIdx.y, kvh = h >> 3;
  int qs = blockIdx.x * 64;
  int kstart = qs - 128;
  const u16* kbase = kb + (long)kvh * S_LEN * HD;
  const u16* vbase = vtb + (long)kvh * HD * S_LEN;
#pragma unroll
  for (int it = 0; it < 6; ++it) {        // K: 192 rows x 64 d
    int idx = t + it * 256;
    int c = idx >> 3, dc = (idx & 7) * 8;
    int j = kstart + c;
    short8 v = {0, 0, 0, 0, 0, 0, 0, 0};
    if (j >= 0) v = *(const short8*)(kbase + (long)j * HD + dc);
    *(short8*)&Kl[c][dc] = v;
  }
#pragma unroll
  for (int it = 0; it < 6; ++it) {        // Vt: 64 rows d x 192 keys
    int idx = t + it * 256;
    int d = idx / 24, c8 = idx % 24;
    int c = c8 * 8;
    int j = kstart + c;                   // vec8 validity uniform (qs mult of 64)
    short8 v = {0, 0, 0, 0, 0, 0, 0, 0};
    if (j >= 0) v = *(const short8*)(vbase + (long)d * S_LEN + j);
    *(short8*)&Vl[d][c] = v;
  }
  __syncthreads();

  int w = t >> 6, l = t & 63;
  int fr = l & 15, fk8 = (l >> 4) * 8, fq = (l >> 4) * 4;
  const u16* qrow = qb + (long)h * S_LEN * HD + (long)(qs + w * 16 + fr) * HD;
  short8 a0 = *(const short8*)(qrow + fk8);
  short8 a1 = *(const short8*)(qrow + 32 + fk8);
  floatx4 sc[12];
#pragma unroll
  for (int ct = 0; ct < 12; ++ct) {
    floatx4 z = {0.f, 0.f, 0.f, 0.f};
    short8 b0 = *(const short8*)&Kl[ct * 16 + fr][fk8];
    short8 b1 = *(const short8*)&Kl[ct * 16 + fr][32 + fk8];
    z = __builtin_amdgcn_mfma_f32_16x16x32_bf16(a0, b0, z, 0, 0, 0);
    z = __builtin_amdgcn_mfma_f32_16x16x32_bf16(a1, b1, z, 0, 0, 0);
    sc[ct] = z;
  }
  __syncthreads();  // all waves done reading Kl before P overwrites it

  u16* Pw = &Kl[0][0] + w * 16 * 200;     // per-wave P tile [16][200]
  float snk = sinks[h];
#pragma unroll
  for (int r = 0; r < 4; ++r) {
    int rloc = w * 16 + fq + r;           // query index within 64-block
    int cmin = rloc + 1;                  // i-j < 128
    int jmin = 128 - qs;                  // j >= 0
    if (jmin > cmin) cmin = jmin;
    int cmax = rloc + 128;                // j <= i
    float vals[12];
    float mx = snk;
#pragma unroll
    for (int ct = 0; ct < 12; ++ct) {
      int c = ct * 16 + fr;
      float v = (c >= cmin && c <= cmax) ? sc[ct][r] * SCALE : -1e30f;
      vals[ct] = v;
      mx = fmaxf(mx, v);
    }
#pragma unroll
    for (int m = 1; m < 16; m <<= 1) mx = fmaxf(mx, __shfl_xor(mx, m));
    float e[12], sum = 0.f;
#pragma unroll
    for (int ct = 0; ct < 12; ++ct) { e[ct] = __expf(vals[ct] - mx); sum += e[ct]; }
#pragma unroll
    for (int m = 1; m < 16; m <<= 1) sum += __shfl_xor(sum, m);
    sum += __expf(snk - mx);
    float inv = 1.f / sum;
#pragma unroll
    for (int ct = 0; ct < 12; ++ct)
      Pw[(fq + r) * 200 + ct * 16 + fr] = f2bf(e[ct] * inv);
  }
  __syncthreads();  // P visible to own wave's b128 reads (and keeps waves aligned)

  floatx4 o[4];
  floatx4 zero = {0.f, 0.f, 0.f, 0.f};
#pragma unroll
  for (int cd = 0; cd < 4; ++cd) o[cd] = zero;
#pragma unroll
  for (int kk = 0; kk < 6; ++kk) {
    short8 pa = *(const short8*)(Pw + fr * 200 + kk * 32 + fk8);
#pragma unroll
    for (int cd = 0; cd < 4; ++cd) {
      short8 bv8 = *(const short8*)&Vl[cd * 16 + fr][kk * 32 + fk8];
      o[cd] = __builtin_amdgcn_mfma_f32_16x16x32_bf16(pa, bv8, o[cd], 0, 0, 0);
    }
  }
#pragma unroll
  for (int cd = 0; cd < 4; ++cd)
#pragma unroll
    for (int r = 0; r < 4; ++r) {
      int srow = qs + w * 16 + fq + r;
      ao[(long)srow * NQ + h * HD + cd * 16 + fr] = f2bf(o[cd][r]);
    }
}

// ---------------- output projection GEMM ----------------
// bm-fastest mapping for the same per-XCD locality reason (B partitioned).
__global__ __launch_bounds__(256) void k_gemm_out(
    const u16* __restrict__ attn, const u16* __restrict__ wot,
    const float* __restrict__ bo, float* __restrict__ out) {
  int sw = xcd_swz(blockIdx.x, gridDim.x);       // 368 blocks = 23 bn x 16 bm
  int bm = (sw & 15) * 128, bn = (sw >> 4) * 128;
  floatx4 acc[4][4];
  gemm_tile(attn + (long)bm * NQ, NQ, wot + (long)bn * NQ, NQ, NQ, acc);
  int t = threadIdx.x, w = t >> 6, l = t & 63;
  int wr = (w >> 1) * 64, wc = (w & 1) * 64, fr = l & 15, fq = (l >> 4) * 4;
#pragma unroll
  for (int i = 0; i < 4; ++i)
#pragma unroll
    for (int j = 0; j < 4; ++j) {
      int ng = bn + wc + j * 16 + fr;
      if (ng >= HID) continue;            // N=2880 tail guard
      float bsv = bo[ng];
#pragma unroll
      for (int r = 0; r < 4; ++r) {
        int srow = bm + wr + i * 16 + fq + r;
        out[(long)srow * HID + ng] = acc[i][j][r] + bsv;
      }
    }
}

extern "C" void kernel_launch(void* const* d_in, const int* in_sizes, int n_in,
                              void* d_out, int out_size, void* d_ws, size_t ws_size,
                              hipStream_t stream) {
  const float* hs    = (const float*)d_in[0];
  const float* cosb  = (const float*)d_in[1];
  const float* sinb  = (const float*)d_in[2];
  const float* wq    = (const float*)d_in[3];
  const float* bq    = (const float*)d_in[4];
  const float* wk    = (const float*)d_in[5];
  const float* bk    = (const float*)d_in[6];
  const float* wv    = (const float*)d_in[7];
  const float* bv    = (const float*)d_in[8];
  const float* wo    = (const float*)d_in[9];
  const float* bo    = (const float*)d_in[10];
  const float* sinks = (const float*)d_in[11];
  float* out = (float*)d_out;

  char* p = (char*)d_ws;
  u16* hsb   = (u16*)p; p += (size_t)S_LEN * HID * 2;
  u16* wqt   = (u16*)p; p += (size_t)NQ * HID * 2;
  u16* wkt   = (u16*)p; p += (size_t)NKVD * HID * 2;
  u16* wvt   = (u16*)p; p += (size_t)NKVD * HID * 2;
  u16* wot   = (u16*)p; p += (size_t)2944 * NQ * 2;   // 23 N-tiles * 128 rows, padded
  u16* qbuf  = (u16*)p; p += (size_t)NH * S_LEN * HD * 2;
  u16* kbuf  = (u16*)p; p += (size_t)NKV * S_LEN * HD * 2;
  u16* vtbuf = (u16*)p; p += (size_t)NKV * HD * S_LEN * 2;
  u16* abuf  = (u16*)p; p += (size_t)S_LEN * NQ * 2;

  k_convert<<<(S_LEN * HID / 4 + 255) / 256, 256, 0, stream>>>(hs, hsb, S_LEN * HID / 4);
  k_transpose<<<dim3(NQ / 32, HID / 32), dim3(32, 8), 0, stream>>>(wq, wqt, HID, NQ);
  k_transpose<<<dim3(NKVD / 32, HID / 32), dim3(32, 8), 0, stream>>>(wk, wkt, HID, NKVD);
  k_transpose<<<dim3(NKVD / 32, HID / 32), dim3(32, 8), 0, stream>>>(wv, wvt, HID, NKVD);
  k_transpose<<<dim3(HID / 32, NQ / 32), dim3(32, 8), 0, stream>>>(wo, wot, NQ, HID);
  k_gemm_qkv<<<(NQ + 2 * NKVD) / 128 * (S_LEN / 128), 256, 0, stream>>>(
      hsb, wqt, wkt, wvt, bq, bk, bv, cosb, sinb, qbuf, kbuf, vtbuf);
  k_attn<<<dim3(S_LEN / 64, NH), 256, 0, stream>>>(qbuf, kbuf, vtbuf, sinks, abuf);
  k_gemm_out<<<23 * 16, 256, 0, stream>>>(abuf, wot, bo, out);
}

// Round 6
// 224.496 us; speedup vs baseline: 1.1228x; 1.1228x over previous
//
#include <hip/hip_runtime.h>
#include <hip/hip_bf16.h>
#include <stdint.h>

#define S_LEN 2048
#define HID 2880
#define NH 64
#define NKV 8
#define HD 64
#define NQ (NH * HD)     // 4096
#define NKVD (NKV * HD)  // 512
#define SCALE 0.125f

typedef unsigned short u16;
typedef __attribute__((ext_vector_type(8))) short short8;
typedef __attribute__((ext_vector_type(4))) float floatx4;

__device__ __forceinline__ u16 f2bf(float f) {
  union { float f; unsigned u; } x; x.f = f;
  unsigned r = x.u + 0x7fffu + ((x.u >> 16) & 1u);
  return (u16)(r >> 16);
}
__device__ __forceinline__ float bf2f(u16 u) {
  union { unsigned u; float f; } x; x.u = ((unsigned)u) << 16;
  return x.f;
}

// bijective XCD-aware block swizzle (m204): contiguous chunk per XCD
__device__ __forceinline__ int xcd_swz(int orig, int nwg) {
  int q = nwg >> 3, r = nwg & 7, xcd = orig & 7, lid = orig >> 3;
  return (xcd < r ? xcd * (q + 1) : r * (q + 1) + (xcd - r) * q) + lid;
}

// global -> LDS async copy, 16B per lane. LDS dest is wave-uniform base;
// HW writes lane i at base + i*16.
__device__ __forceinline__ void gl2lds16(const void* g, void* l) {
  __builtin_amdgcn_global_load_lds(
      (__attribute__((address_space(1))) unsigned int*)(uintptr_t)g,
      (__attribute__((address_space(3))) unsigned int*)(unsigned int)(uintptr_t)l,
      16, 0, 0);
}

// ---------------- convert f32 -> bf16 ----------------
__global__ void k_convert(const float* __restrict__ in, u16* __restrict__ out, int n4) {
  int i = blockIdx.x * blockDim.x + threadIdx.x;
  if (i >= n4) return;
  float4 v = *((const float4*)in + i);
  ushort4 o;
  o.x = f2bf(v.x); o.y = f2bf(v.y); o.z = f2bf(v.z); o.w = f2bf(v.w);
  *(ushort4*)(out + (size_t)i * 4) = o;
}

// ---------------- transpose f32[R][C] -> bf16[C][R] ----------------
__global__ void k_transpose(const float* __restrict__ in, u16* __restrict__ out, int R, int C) {
  __shared__ float tile[32][33];
  int bx = blockIdx.x * 32, by = blockIdx.y * 32;
  int tx = threadIdx.x, ty = threadIdx.y;
#pragma unroll
  for (int i = 0; i < 4; ++i)
    tile[ty + i * 8][tx] = in[(long)(by + ty + i * 8) * C + bx + tx];
  __syncthreads();
#pragma unroll
  for (int i = 0; i < 4; ++i)
    out[(long)(bx + ty + i * 8) * R + by + tx] = f2bf(tile[tx][ty + i * 8]);
}

// ---------------- 128x128 bf16 MFMA GEMM core ----------------
// Ring-3 (48 KB LDS -> 3 blocks/CU co-residency, the r4-measured 2.4 TB/s
// concurrency regime) + counted vmcnt(4): loads for tile t+1 stay in flight
// across the barrier; never drains to 0 in steady state.
// Race safety: each wave waits its own vmcnt(4) before s_barrier => after the
// barrier all 16 loads of tile t have landed. STAGE(t+2) overwrites buf(t-1),
// legal because all waves finished compute(t-1) before arriving at barrier t.
__device__ __forceinline__ void gemm_tile(const u16* __restrict__ Abase, int lda,
                                          const u16* __restrict__ Bbase, int ldb,
                                          int kloop, floatx4 acc[4][4]) {
  __shared__ __align__(16) u16 As[3][128][32];
  __shared__ __align__(16) u16 Bs[3][128][32];
  const int t = threadIdx.x;
  const int w = t >> 6, l = t & 63;
  const int srow = w * 16 + (l >> 2);   // staging row within 64-row pass
  const int scol = (l & 3) * 8;         // staging col (bf16 elems)
  const int wr = (w >> 1) * 64, wc = (w & 1) * 64;
  const int fr = l & 15, fk8 = (l >> 4) * 8;
  floatx4 zero = {0.f, 0.f, 0.f, 0.f};
#pragma unroll
  for (int i = 0; i < 4; ++i)
#pragma unroll
    for (int j = 0; j < 4; ++j) acc[i][j] = zero;

  const u16* Ar0 = Abase + (long)srow * lda + scol;
  const u16* Ar1 = Abase + (long)(64 + srow) * lda + scol;
  const u16* Br0 = Bbase + (long)srow * ldb + scol;
  const u16* Br1 = Bbase + (long)(64 + srow) * ldb + scol;

#define STAGE(buf, kt) do {                              \
    long ko_ = (long)(kt) * 32;                          \
    gl2lds16(Ar0 + ko_, &As[buf][w * 16][0]);            \
    gl2lds16(Ar1 + ko_, &As[buf][64 + w * 16][0]);       \
    gl2lds16(Br0 + ko_, &Bs[buf][w * 16][0]);            \
    gl2lds16(Br1 + ko_, &Bs[buf][64 + w * 16][0]);       \
  } while (0)

  const int nk = kloop >> 5;            // nk >= 2 always here
  STAGE(0, 0);
  STAGE(1, 1);
  int cur = 0, nxt = 1, fut = 2;
  for (int kt = 0; kt < nk; ++kt) {
    if (kt + 1 < nk) { asm volatile("s_waitcnt vmcnt(4)" ::: "memory"); }
    else             { asm volatile("s_waitcnt vmcnt(0)" ::: "memory"); }
    asm volatile("s_barrier" ::: "memory");   // tile `cur` resident for ALL waves
    if (kt + 2 < nk) STAGE(fut, kt + 2);      // refill: 8 outstanding again
    short8 af[4], bf8[4];
#pragma unroll
    for (int i = 0; i < 4; ++i) af[i] = *(const short8*)&As[cur][wr + i * 16 + fr][fk8];
#pragma unroll
    for (int j = 0; j < 4; ++j) bf8[j] = *(const short8*)&Bs[cur][wc + j * 16 + fr][fk8];
#pragma unroll
    for (int i = 0; i < 4; ++i)
#pragma unroll
      for (int j = 0; j < 4; ++j)
        acc[i][j] = __builtin_amdgcn_mfma_f32_16x16x32_bf16(af[i], bf8[j], acc[i][j], 0, 0, 0);
    int tmp = cur; cur = nxt; nxt = fut; fut = tmp;
  }
#undef STAGE
}

// ---------------- QKV GEMM + bias + fused RoPE, scatter epilogue ----------------
// q -> qbuf[h][s][d] (rope'd), k -> kbuf[kvh][s][d] (rope'd), v -> vtbuf[kvh][d][s]
// Block mapping: bm-FASTEST (sw&15) so each XCD chunk (80 blocks = 5 bn x 16 bm)
// touches only 5 B-panels (3.7 MB, L2-resident) + the shared A (11.8 MB) --
// per-XCD compulsory ~15.5 MB vs 31 MB with bn-fastest (r4 measured 226 MB,
// r5 measured 132 MB FETCH).
__global__ __launch_bounds__(256) void k_gemm_qkv(
    const u16* __restrict__ hsb, const u16* __restrict__ wqt,
    const u16* __restrict__ wkt, const u16* __restrict__ wvt,
    const float* __restrict__ bq, const float* __restrict__ bk, const float* __restrict__ bv,
    const float* __restrict__ cosb, const float* __restrict__ sinb,
    u16* __restrict__ qbuf, u16* __restrict__ kbuf, u16* __restrict__ vtbuf) {
  int sw = xcd_swz(blockIdx.x, gridDim.x);       // 640 blocks
  int bm = (sw & 15) * 128, bn = (sw >> 4) * 128;
  const u16* Bt; const float* bias;
  if (bn < NQ)              { Bt = wqt + (long)bn * HID;               bias = bq + bn; }
  else if (bn < NQ + NKVD)  { Bt = wkt + (long)(bn - NQ) * HID;        bias = bk + (bn - NQ); }
  else                      { Bt = wvt + (long)(bn - NQ - NKVD) * HID; bias = bv + (bn - NQ - NKVD); }
  floatx4 acc[4][4];
  gemm_tile(hsb + (long)bm * HID, HID, Bt, HID, HID, acc);
  int t = threadIdx.x, w = t >> 6, l = t & 63;
  int wr = (w >> 1) * 64, wc = (w & 1) * 64, fr = l & 15, fq = (l >> 4) * 4;
  if (bn < NQ + NKVD) {
    // q/k path with fused RoPE. Head window = [bn+wc, bn+wc+64), 64-aligned.
    int ng0 = bn + wc;                         // head base (global col)
    u16* hbase;
    if (ng0 < NQ) hbase = qbuf + (long)(ng0 >> 6) * S_LEN * HD;
    else          hbase = kbuf + (long)((ng0 - NQ) >> 6) * S_LEN * HD;
#pragma unroll
    for (int i = 0; i < 4; ++i)
#pragma unroll
      for (int r = 0; r < 4; ++r) {
        int srow = bm + wr + i * 16 + fq + r;
        const float* crow = cosb + (long)srow * HD;
        const float* srw  = sinb + (long)srow * HD;
#pragma unroll
        for (int j = 0; j < 2; ++j) {
          int dlo = j * 16 + fr;               // in [0,32)
          float c  = crow[dlo];
          float si = srw[dlo];
          float xl = acc[i][j][r]     + bias[wc + j * 16 + fr];
          float xh = acc[i][j + 2][r] + bias[wc + (j + 2) * 16 + fr];
          u16 nl = f2bf(xl * c - xh * si);
          u16 nh = f2bf(xh * c + xl * si);
          hbase[(long)srow * HD + dlo]      = nl;
          hbase[(long)srow * HD + dlo + 32] = nh;
        }
      }
  } else {
    // v path: transposed scatter vtbuf[kvh][d][s]
#pragma unroll
    for (int i = 0; i < 4; ++i)
#pragma unroll
      for (int j = 0; j < 4; ++j) {
        int ncol = wc + j * 16 + fr;
        int n3 = bn + ncol - NQ - NKVD;
        float bsv = bias[ncol];
#pragma unroll
        for (int r = 0; r < 4; ++r) {
          int srow = bm + wr + i * 16 + fq + r;
          vtbuf[(long)(n3 >> 6) * HD * S_LEN + (long)(n3 & 63) * S_LEN + srow] =
              f2bf(acc[i][j][r] + bsv);
        }
      }
  }
}

// ---------------- sliding-window GQA attention with sinks ----------------
// grid (S/64, NH); block 256 (4 waves x 16 queries). Window keys staged: 192.
__global__ __launch_bounds__(256) void k_attn(
    const u16* __restrict__ qb, const u16* __restrict__ kb, const u16* __restrict__ vtb,
    const float* __restrict__ sinks, u16* __restrict__ ao) {
  __shared__ __align__(16) u16 Kl[192][72];   // 27648 B; reused as P[4][16][200] after QK
  __shared__ __align__(16) u16 Vl[64][200];   // V transposed: [d][key]
  int t = threadIdx.x;
  int h = blockIdx.y, kvh = h >> 3;
  int qs = blockIdx.x * 64;
  int kstart = qs - 128;
  const u16* kbase = kb + (long)kvh * S_LEN * HD;
  const u16* vbase = vtb + (long)kvh * HD * S_LEN;
#pragma unroll
  for (int it = 0; it < 6; ++it) {        // K: 192 rows x 64 d
    int idx = t + it * 256;
    int c = idx >> 3, dc = (idx & 7) * 8;
    int j = kstart + c;
    short8 v = {0, 0, 0, 0, 0, 0, 0, 0};
    if (j >= 0) v = *(const short8*)(kbase + (long)j * HD + dc);
    *(short8*)&Kl[c][dc] = v;
  }
#pragma unroll
  for (int it = 0; it < 6; ++it) {        // Vt: 64 rows d x 192 keys
    int idx = t + it * 256;
    int d = idx / 24, c8 = idx % 24;
    int c = c8 * 8;
    int j = kstart + c;                   // vec8 validity uniform (qs mult of 64)
    short8 v = {0, 0, 0, 0, 0, 0, 0, 0};
    if (j >= 0) v = *(const short8*)(vbase + (long)d * S_LEN + j);
    *(short8*)&Vl[d][c] = v;
  }
  __syncthreads();

  int w = t >> 6, l = t & 63;
  int fr = l & 15, fk8 = (l >> 4) * 8, fq = (l >> 4) * 4;
  const u16* qrow = qb + (long)h * S_LEN * HD + (long)(qs + w * 16 + fr) * HD;
  short8 a0 = *(const short8*)(qrow + fk8);
  short8 a1 = *(const short8*)(qrow + 32 + fk8);
  floatx4 sc[12];
#pragma unroll
  for (int ct = 0; ct < 12; ++ct) {
    floatx4 z = {0.f, 0.f, 0.f, 0.f};
    short8 b0 = *(const short8*)&Kl[ct * 16 + fr][fk8];
    short8 b1 = *(const short8*)&Kl[ct * 16 + fr][32 + fk8];
    z = __builtin_amdgcn_mfma_f32_16x16x32_bf16(a0, b0, z, 0, 0, 0);
    z = __builtin_amdgcn_mfma_f32_16x16x32_bf16(a1, b1, z, 0, 0, 0);
    sc[ct] = z;
  }
  __syncthreads();  // all waves done reading Kl before P overwrites it

  u16* Pw = &Kl[0][0] + w * 16 * 200;     // per-wave P tile [16][200]
  float snk = sinks[h];
#pragma unroll
  for (int r = 0; r < 4; ++r) {
    int rloc = w * 16 + fq + r;           // query index within 64-block
    int cmin = rloc + 1;                  // i-j < 128
    int jmin = 128 - qs;                  // j >= 0
    if (jmin > cmin) cmin = jmin;
    int cmax = rloc + 128;                // j <= i
    float vals[12];
    float mx = snk;
#pragma unroll
    for (int ct = 0; ct < 12; ++ct) {
      int c = ct * 16 + fr;
      float v = (c >= cmin && c <= cmax) ? sc[ct][r] * SCALE : -1e30f;
      vals[ct] = v;
      mx = fmaxf(mx, v);
    }
#pragma unroll
    for (int m = 1; m < 16; m <<= 1) mx = fmaxf(mx, __shfl_xor(mx, m));
    float e[12], sum = 0.f;
#pragma unroll
    for (int ct = 0; ct < 12; ++ct) { e[ct] = __expf(vals[ct] - mx); sum += e[ct]; }
#pragma unroll
    for (int m = 1; m < 16; m <<= 1) sum += __shfl_xor(sum, m);
    sum += __expf(snk - mx);
    float inv = 1.f / sum;
#pragma unroll
    for (int ct = 0; ct < 12; ++ct)
      Pw[(fq + r) * 200 + ct * 16 + fr] = f2bf(e[ct] * inv);
  }
  __syncthreads();  // P visible to own wave's b128 reads (and keeps waves aligned)

  floatx4 o[4];
  floatx4 zero = {0.f, 0.f, 0.f, 0.f};
#pragma unroll
  for (int cd = 0; cd < 4; ++cd) o[cd] = zero;
#pragma unroll
  for (int kk = 0; kk < 6; ++kk) {
    short8 pa = *(const short8*)(Pw + fr * 200 + kk * 32 + fk8);
#pragma unroll
    for (int cd = 0; cd < 4; ++cd) {
      short8 bv8 = *(const short8*)&Vl[cd * 16 + fr][kk * 32 + fk8];
      o[cd] = __builtin_amdgcn_mfma_f32_16x16x32_bf16(pa, bv8, o[cd], 0, 0, 0);
    }
  }
#pragma unroll
  for (int cd = 0; cd < 4; ++cd)
#pragma unroll
    for (int r = 0; r < 4; ++r) {
      int srow = qs + w * 16 + fq + r;
      ao[(long)srow * NQ + h * HD + cd * 16 + fr] = f2bf(o[cd][r]);
    }
}

// ---------------- output projection GEMM ----------------
// bm-fastest mapping for the same per-XCD locality reason (B partitioned).
__global__ __launch_bounds__(256) void k_gemm_out(
    const u16* __restrict__ attn, const u16* __restrict__ wot,
    const float* __restrict__ bo, float* __restrict__ out) {
  int sw = xcd_swz(blockIdx.x, gridDim.x);       // 368 blocks = 23 bn x 16 bm
  int bm = (sw & 15) * 128, bn = (sw >> 4) * 128;
  floatx4 acc[4][4];
  gemm_tile(attn + (long)bm * NQ, NQ, wot + (long)bn * NQ, NQ, NQ, acc);
  int t = threadIdx.x, w = t >> 6, l = t & 63;
  int wr = (w >> 1) * 64, wc = (w & 1) * 64, fr = l & 15, fq = (l >> 4) * 4;
#pragma unroll
  for (int i = 0; i < 4; ++i)
#pragma unroll
    for (int j = 0; j < 4; ++j) {
      int ng = bn + wc + j * 16 + fr;
      if (ng >= HID) continue;            // N=2880 tail guard
      float bsv = bo[ng];
#pragma unroll
      for (int r = 0; r < 4; ++r) {
        int srow = bm + wr + i * 16 + fq + r;
        out[(long)srow * HID + ng] = acc[i][j][r] + bsv;
      }
    }
}

extern "C" void kernel_launch(void* const* d_in, const int* in_sizes, int n_in,
                              void* d_out, int out_size, void* d_ws, size_t ws_size,
                              hipStream_t stream) {
  const float* hs    = (const float*)d_in[0];
  const float* cosb  = (const float*)d_in[1];
  const float* sinb  = (const float*)d_in[2];
  const float* wq    = (const float*)d_in[3];
  const float* bq    = (const float*)d_in[4];
  const float* wk    = (const float*)d_in[5];
  const float* bk    = (const float*)d_in[6];
  const float* wv    = (const float*)d_in[7];
  const float* bv    = (const float*)d_in[8];
  const float* wo    = (const float*)d_in[9];
  const float* bo    = (const float*)d_in[10];
  const float* sinks = (const float*)d_in[11];
  float* out = (float*)d_out;

  char* p = (char*)d_ws;
  u16* hsb   = (u16*)p; p += (size_t)S_LEN * HID * 2;
  u16* wqt   = (u16*)p; p += (size_t)NQ * HID * 2;
  u16* wkt   = (u16*)p; p += (size_t)NKVD * HID * 2;
  u16* wvt   = (u16*)p; p += (size_t)NKVD * HID * 2;
  u16* wot   = (u16*)p; p += (size_t)2944 * NQ * 2;   // 23 N-tiles * 128 rows, padded
  u16* qbuf  = (u16*)p; p += (size_t)NH * S_LEN * HD * 2;
  u16* kbuf  = (u16*)p; p += (size_t)NKV * S_LEN * HD * 2;
  u16* vtbuf = (u16*)p; p += (size_t)NKV * HD * S_LEN * 2;
  u16* abuf  = (u16*)p; p += (size_t)S_LEN * NQ * 2;

  k_convert<<<(S_LEN * HID / 4 + 255) / 256, 256, 0, stream>>>(hs, hsb, S_LEN * HID / 4);
  k_transpose<<<dim3(NQ / 32, HID / 32), dim3(32, 8), 0, stream>>>(wq, wqt, HID, NQ);
  k_transpose<<<dim3(NKVD / 32, HID / 32), dim3(32, 8), 0, stream>>>(wk, wkt, HID, NKVD);
  k_transpose<<<dim3(NKVD / 32, HID / 32), dim3(32, 8), 0, stream>>>(wv, wvt, HID, NKVD);
  k_transpose<<<dim3(HID / 32, NQ / 32), dim3(32, 8), 0, stream>>>(wo, wot, NQ, HID);
  k_gemm_qkv<<<(NQ + 2 * NKVD) / 128 * (S_LEN / 128), 256, 0, stream>>>(
      hsb, wqt, wkt, wvt, bq, bk, bv, cosb, sinb, qbuf, kbuf, vtbuf);
  k_attn<<<dim3(S_LEN / 64, NH), 256, 0, stream>>>(qbuf, kbuf, vtbuf, sinks, abuf);
  k_gemm_out<<<23 * 16, 256, 0, stream>>>(abuf, wot, bo, out);
}

// Round 7
// 224.150 us; speedup vs baseline: 1.1245x; 1.0015x over previous
//
#include <hip/hip_runtime.h>
#include <hip/hip_bf16.h>
#include <stdint.h>

#define S_LEN 2048
#define HID 2880
#define NH 64
#define NKV 8
#define HD 64
#define NQ (NH * HD)     // 4096
#define NKVD (NKV * HD)  // 512
#define SCALE 0.125f

typedef unsigned short u16;
typedef __attribute__((ext_vector_type(8))) short short8;
typedef __attribute__((ext_vector_type(4))) float floatx4;

__device__ __forceinline__ u16 f2bf(float f) {
  union { float f; unsigned u; } x; x.f = f;
  unsigned r = x.u + 0x7fffu + ((x.u >> 16) & 1u);
  return (u16)(r >> 16);
}
__device__ __forceinline__ float bf2f(u16 u) {
  union { unsigned u; float f; } x; x.u = ((unsigned)u) << 16;
  return x.f;
}

// bijective XCD-aware block swizzle (m204): contiguous chunk per XCD
__device__ __forceinline__ int xcd_swz(int orig, int nwg) {
  int q = nwg >> 3, r = nwg & 7, xcd = orig & 7, lid = orig >> 3;
  return (xcd < r ? xcd * (q + 1) : r * (q + 1) + (xcd - r) * q) + lid;
}

// global -> LDS async copy, 16B per lane. LDS dest is wave-uniform base;
// HW writes lane i at base + i*16.
__device__ __forceinline__ void gl2lds16(const void* g, void* l) {
  __builtin_amdgcn_global_load_lds(
      (__attribute__((address_space(1))) unsigned int*)(uintptr_t)g,
      (__attribute__((address_space(3))) unsigned int*)(unsigned int)(uintptr_t)l,
      16, 0, 0);
}

// ---------------- convert f32 -> bf16 ----------------
__global__ void k_convert(const float* __restrict__ in, u16* __restrict__ out, int n4) {
  int i = blockIdx.x * blockDim.x + threadIdx.x;
  if (i >= n4) return;
  float4 v = *((const float4*)in + i);
  ushort4 o;
  o.x = f2bf(v.x); o.y = f2bf(v.y); o.z = f2bf(v.z); o.w = f2bf(v.w);
  *(ushort4*)(out + (size_t)i * 4) = o;
}

// ---------------- transpose f32[R][C] -> bf16[C][R] ----------------
__global__ void k_transpose(const float* __restrict__ in, u16* __restrict__ out, int R, int C) {
  __shared__ float tile[32][33];
  int bx = blockIdx.x * 32, by = blockIdx.y * 32;
  int tx = threadIdx.x, ty = threadIdx.y;
#pragma unroll
  for (int i = 0; i < 4; ++i)
    tile[ty + i * 8][tx] = in[(long)(by + ty + i * 8) * C + bx + tx];
  __syncthreads();
#pragma unroll
  for (int i = 0; i < 4; ++i)
    out[(long)(bx + ty + i * 8) * R + by + tx] = f2bf(tile[tx][ty + i * 8]);
}

// ---------------- 128x128 bf16 MFMA GEMM core ----------------
// Ring-3 (48 KB LDS, 3 blocks/CU capacity >= grid's 2.5/CU) + counted vmcnt(4).
// NEW (r7): zero-cost LDS bank-conflict swizzle (T2 adapted to 64B rows).
//   Store k-block kb of row r at slot kb ^ s(r), s(r) = (r>>1)&3 (16B slots).
//   Both sides fold to per-lane compile-time constants:
//     stage source slot: (l&3) ^ ((l>>3)&3)   [since s(stage row(l)) = (l>>3)&3]
//     frag read  slot:   (l>>4) ^ ((l>>1)&3)  [since s(frag row(l))  = (l>>1)&3]
//   Bank spread: 16 lanes -> 8 banks x 2-way = conflict-free (m136: 2-way free).
//   Source permutation stays within each row's 64B line -> coalescing unchanged.
// Race safety unchanged from r6 (each wave waits own vmcnt(4) before s_barrier;
// STAGE(t+2) overwrites buf(t-1) whose readers finished before barrier t).
__device__ __forceinline__ void gemm_tile(const u16* __restrict__ Abase, int lda,
                                          const u16* __restrict__ Bbase, int ldb,
                                          int kloop, floatx4 acc[4][4]) {
  __shared__ __align__(16) u16 As[3][128][32];
  __shared__ __align__(16) u16 Bs[3][128][32];
  const int t = threadIdx.x;
  const int w = t >> 6, l = t & 63;
  const int srow = w * 16 + (l >> 2);               // staging row within 64-row pass
  const int scol = (((l & 3) ^ ((l >> 3) & 3))) * 8; // pre-swizzled source k-slot
  const int wr = (w >> 1) * 64, wc = (w & 1) * 64;
  const int fr = l & 15;
  const int fk8 = (((l >> 4) ^ ((l >> 1) & 3))) * 8; // swizzled read k-slot
  floatx4 zero = {0.f, 0.f, 0.f, 0.f};
#pragma unroll
  for (int i = 0; i < 4; ++i)
#pragma unroll
    for (int j = 0; j < 4; ++j) acc[i][j] = zero;

  const u16* Ar0 = Abase + (long)srow * lda + scol;
  const u16* Ar1 = Abase + (long)(64 + srow) * lda + scol;
  const u16* Br0 = Bbase + (long)srow * ldb + scol;
  const u16* Br1 = Bbase + (long)(64 + srow) * ldb + scol;

#define STAGE(buf, kt) do {                              \
    long ko_ = (long)(kt) * 32;                          \
    gl2lds16(Ar0 + ko_, &As[buf][w * 16][0]);            \
    gl2lds16(Ar1 + ko_, &As[buf][64 + w * 16][0]);       \
    gl2lds16(Br0 + ko_, &Bs[buf][w * 16][0]);            \
    gl2lds16(Br1 + ko_, &Bs[buf][64 + w * 16][0]);       \
  } while (0)

  const int nk = kloop >> 5;            // nk >= 2 always here
  STAGE(0, 0);
  STAGE(1, 1);
  int cur = 0, nxt = 1, fut = 2;
  for (int kt = 0; kt < nk; ++kt) {
    if (kt + 1 < nk) { asm volatile("s_waitcnt vmcnt(4)" ::: "memory"); }
    else             { asm volatile("s_waitcnt vmcnt(0)" ::: "memory"); }
    asm volatile("s_barrier" ::: "memory");   // tile `cur` resident for ALL waves
    if (kt + 2 < nk) STAGE(fut, kt + 2);      // refill: 8 outstanding again
    short8 af[4], bf8[4];
#pragma unroll
    for (int i = 0; i < 4; ++i) af[i] = *(const short8*)&As[cur][wr + i * 16 + fr][fk8];
#pragma unroll
    for (int j = 0; j < 4; ++j) bf8[j] = *(const short8*)&Bs[cur][wc + j * 16 + fr][fk8];
#pragma unroll
    for (int i = 0; i < 4; ++i)
#pragma unroll
      for (int j = 0; j < 4; ++j)
        acc[i][j] = __builtin_amdgcn_mfma_f32_16x16x32_bf16(af[i], bf8[j], acc[i][j], 0, 0, 0);
    int tmp = cur; cur = nxt; nxt = fut; fut = tmp;
  }
#undef STAGE
}

// ---------------- QKV GEMM + bias + fused RoPE, scatter epilogue ----------------
// q -> qbuf[h][s][d] (rope'd), k -> kbuf[kvh][s][d] (rope'd), v -> vtbuf[kvh][d][s]
// Block mapping: bm-FASTEST (sw&15) so each XCD chunk (80 blocks = 5 bn x 16 bm)
// touches only 5 B-panels (3.7 MB, L2-resident) + the shared A (11.8 MB).
__global__ __launch_bounds__(256) void k_gemm_qkv(
    const u16* __restrict__ hsb, const u16* __restrict__ wqt,
    const u16* __restrict__ wkt, const u16* __restrict__ wvt,
    const float* __restrict__ bq, const float* __restrict__ bk, const float* __restrict__ bv,
    const float* __restrict__ cosb, const float* __restrict__ sinb,
    u16* __restrict__ qbuf, u16* __restrict__ kbuf, u16* __restrict__ vtbuf) {
  int sw = xcd_swz(blockIdx.x, gridDim.x);       // 640 blocks
  int bm = (sw & 15) * 128, bn = (sw >> 4) * 128;
  const u16* Bt; const float* bias;
  if (bn < NQ)              { Bt = wqt + (long)bn * HID;               bias = bq + bn; }
  else if (bn < NQ + NKVD)  { Bt = wkt + (long)(bn - NQ) * HID;        bias = bk + (bn - NQ); }
  else                      { Bt = wvt + (long)(bn - NQ - NKVD) * HID; bias = bv + (bn - NQ - NKVD); }
  floatx4 acc[4][4];
  gemm_tile(hsb + (long)bm * HID, HID, Bt, HID, HID, acc);
  int t = threadIdx.x, w = t >> 6, l = t & 63;
  int wr = (w >> 1) * 64, wc = (w & 1) * 64, fr = l & 15, fq = (l >> 4) * 4;
  if (bn < NQ + NKVD) {
    // q/k path with fused RoPE. Head window = [bn+wc, bn+wc+64), 64-aligned.
    int ng0 = bn + wc;                         // head base (global col)
    u16* hbase;
    if (ng0 < NQ) hbase = qbuf + (long)(ng0 >> 6) * S_LEN * HD;
    else          hbase = kbuf + (long)((ng0 - NQ) >> 6) * S_LEN * HD;
#pragma unroll
    for (int i = 0; i < 4; ++i)
#pragma unroll
      for (int r = 0; r < 4; ++r) {
        int srow = bm + wr + i * 16 + fq + r;
        const float* crow = cosb + (long)srow * HD;
        const float* srw  = sinb + (long)srow * HD;
#pragma unroll
        for (int j = 0; j < 2; ++j) {
          int dlo = j * 16 + fr;               // in [0,32)
          float c  = crow[dlo];
          float si = srw[dlo];
          float xl = acc[i][j][r]     + bias[wc + j * 16 + fr];
          float xh = acc[i][j + 2][r] + bias[wc + (j + 2) * 16 + fr];
          u16 nl = f2bf(xl * c - xh * si);
          u16 nh = f2bf(xh * c + xl * si);
          hbase[(long)srow * HD + dlo]      = nl;
          hbase[(long)srow * HD + dlo + 32] = nh;
        }
      }
  } else {
    // v path: transposed scatter vtbuf[kvh][d][s]
#pragma unroll
    for (int i = 0; i < 4; ++i)
#pragma unroll
      for (int j = 0; j < 4; ++j) {
        int ncol = wc + j * 16 + fr;
        int n3 = bn + ncol - NQ - NKVD;
        float bsv = bias[ncol];
#pragma unroll
        for (int r = 0; r < 4; ++r) {
          int srow = bm + wr + i * 16 + fq + r;
          vtbuf[(long)(n3 >> 6) * HD * S_LEN + (long)(n3 & 63) * S_LEN + srow] =
              f2bf(acc[i][j][r] + bsv);
        }
      }
  }
}

// ---------------- sliding-window GQA attention with sinks ----------------
// grid (S/64, NH); block 256 (4 waves x 16 queries). Window keys staged: 192.
__global__ __launch_bounds__(256) void k_attn(
    const u16* __restrict__ qb, const u16* __restrict__ kb, const u16* __restrict__ vtb,
    const float* __restrict__ sinks, u16* __restrict__ ao) {
  __shared__ __align__(16) u16 Kl[192][72];   // 27648 B; reused as P[4][16][200] after QK
  __shared__ __align__(16) u16 Vl[64][200];   // V transposed: [d][key]
  int t = threadIdx.x;
  int h = blockIdx.y, kvh = h >> 3;
  int qs = blockIdx.x * 64;
  int kstart = qs - 128;
  const u16* kbase = kb + (long)kvh * S_LEN * HD;
  const u16* vbase = vtb + (long)kvh * HD * S_LEN;
#pragma unroll
  for (int it = 0; it < 6; ++it) {        // K: 192 rows x 64 d
    int idx = t + it * 256;
    int c = idx >> 3, dc = (idx & 7) * 8;
    int j = kstart + c;
    short8 v = {0, 0, 0, 0, 0, 0, 0, 0};
    if (j >= 0) v = *(const short8*)(kbase + (long)j * HD + dc);
    *(short8*)&Kl[c][dc] = v;
  }
#pragma unroll
  for (int it = 0; it < 6; ++it) {        // Vt: 64 rows d x 192 keys
    int idx = t + it * 256;
    int d = idx / 24, c8 = idx % 24;
    int c = c8 * 8;
    int j = kstart + c;                   // vec8 validity uniform (qs mult of 64)
    short8 v = {0, 0, 0, 0, 0, 0, 0, 0};
    if (j >= 0) v = *(const short8*)(vbase + (long)d * S_LEN + j);
    *(short8*)&Vl[d][c] = v;
  }
  __syncthreads();

  int w = t >> 6, l = t & 63;
  int fr = l & 15, fk8 = (l >> 4) * 8, fq = (l >> 4) * 4;
  const u16* qrow = qb + (long)h * S_LEN * HD + (long)(qs + w * 16 + fr) * HD;
  short8 a0 = *(const short8*)(qrow + fk8);
  short8 a1 = *(const short8*)(qrow + 32 + fk8);
  floatx4 sc[12];
#pragma unroll
  for (int ct = 0; ct < 12; ++ct) {
    floatx4 z = {0.f, 0.f, 0.f, 0.f};
    short8 b0 = *(const short8*)&Kl[ct * 16 + fr][fk8];
    short8 b1 = *(const short8*)&Kl[ct * 16 + fr][32 + fk8];
    z = __builtin_amdgcn_mfma_f32_16x16x32_bf16(a0, b0, z, 0, 0, 0);
    z = __builtin_amdgcn_mfma_f32_16x16x32_bf16(a1, b1, z, 0, 0, 0);
    sc[ct] = z;
  }
  __syncthreads();  // all waves done reading Kl before P overwrites it

  u16* Pw = &Kl[0][0] + w * 16 * 200;     // per-wave P tile [16][200]
  float snk = sinks[h];
#pragma unroll
  for (int r = 0; r < 4; ++r) {
    int rloc = w * 16 + fq + r;           // query index within 64-block
    int cmin = rloc + 1;                  // i-j < 128
    int jmin = 128 - qs;                  // j >= 0
    if (jmin > cmin) cmin = jmin;
    int cmax = rloc + 128;                // j <= i
    float vals[12];
    float mx = snk;
#pragma unroll
    for (int ct = 0; ct < 12; ++ct) {
      int c = ct * 16 + fr;
      float v = (c >= cmin && c <= cmax) ? sc[ct][r] * SCALE : -1e30f;
      vals[ct] = v;
      mx = fmaxf(mx, v);
    }
#pragma unroll
    for (int m = 1; m < 16; m <<= 1) mx = fmaxf(mx, __shfl_xor(mx, m));
    float e[12], sum = 0.f;
#pragma unroll
    for (int ct = 0; ct < 12; ++ct) { e[ct] = __expf(vals[ct] - mx); sum += e[ct]; }
#pragma unroll
    for (int m = 1; m < 16; m <<= 1) sum += __shfl_xor(sum, m);
    sum += __expf(snk - mx);
    float inv = 1.f / sum;
#pragma unroll
    for (int ct = 0; ct < 12; ++ct)
      Pw[(fq + r) * 200 + ct * 16 + fr] = f2bf(e[ct] * inv);
  }
  __syncthreads();  // P visible to own wave's b128 reads (and keeps waves aligned)

  floatx4 o[4];
  floatx4 zero = {0.f, 0.f, 0.f, 0.f};
#pragma unroll
  for (int cd = 0; cd < 4; ++cd) o[cd] = zero;
#pragma unroll
  for (int kk = 0; kk < 6; ++kk) {
    short8 pa = *(const short8*)(Pw + fr * 200 + kk * 32 + fk8);
#pragma unroll
    for (int cd = 0; cd < 4; ++cd) {
      short8 bv8 = *(const short8*)&Vl[cd * 16 + fr][kk * 32 + fk8];
      o[cd] = __builtin_amdgcn_mfma_f32_16x16x32_bf16(pa, bv8, o[cd], 0, 0, 0);
    }
  }
#pragma unroll
  for (int cd = 0; cd < 4; ++cd)
#pragma unroll
    for (int r = 0; r < 4; ++r) {
      int srow = qs + w * 16 + fq + r;
      ao[(long)srow * NQ + h * HD + cd * 16 + fr] = f2bf(o[cd][r]);
    }
}

// ---------------- output projection GEMM ----------------
// bm-fastest mapping for the same per-XCD locality reason (B partitioned).
__global__ __launch_bounds__(256) void k_gemm_out(
    const u16* __restrict__ attn, const u16* __restrict__ wot,
    const float* __restrict__ bo, float* __restrict__ out) {
  int sw = xcd_swz(blockIdx.x, gridDim.x);       // 368 blocks = 23 bn x 16 bm
  int bm = (sw & 15) * 128, bn = (sw >> 4) * 128;
  floatx4 acc[4][4];
  gemm_tile(attn + (long)bm * NQ, NQ, wot + (long)bn * NQ, NQ, NQ, acc);
  int t = threadIdx.x, w = t >> 6, l = t & 63;
  int wr = (w >> 1) * 64, wc = (w & 1) * 64, fr = l & 15, fq = (l >> 4) * 4;
#pragma unroll
  for (int i = 0; i < 4; ++i)
#pragma unroll
    for (int j = 0; j < 4; ++j) {
      int ng = bn + wc + j * 16 + fr;
      if (ng >= HID) continue;            // N=2880 tail guard
      float bsv = bo[ng];
#pragma unroll
      for (int r = 0; r < 4; ++r) {
        int srow = bm + wr + i * 16 + fq + r;
        out[(long)srow * HID + ng] = acc[i][j][r] + bsv;
      }
    }
}

extern "C" void kernel_launch(void* const* d_in, const int* in_sizes, int n_in,
                              void* d_out, int out_size, void* d_ws, size_t ws_size,
                              hipStream_t stream) {
  const float* hs    = (const float*)d_in[0];
  const float* cosb  = (const float*)d_in[1];
  const float* sinb  = (const float*)d_in[2];
  const float* wq    = (const float*)d_in[3];
  const float* bq    = (const float*)d_in[4];
  const float* wk    = (const float*)d_in[5];
  const float* bk    = (const float*)d_in[6];
  const float* wv    = (const float*)d_in[7];
  const float* bv    = (const float*)d_in[8];
  const float* wo    = (const float*)d_in[9];
  const float* bo    = (const float*)d_in[10];
  const float* sinks = (const float*)d_in[11];
  float* out = (float*)d_out;

  char* p = (char*)d_ws;
  u16* hsb   = (u16*)p; p += (size_t)S_LEN * HID * 2;
  u16* wqt   = (u16*)p; p += (size_t)NQ * HID * 2;
  u16* wkt   = (u16*)p; p += (size_t)NKVD * HID * 2;
  u16* wvt   = (u16*)p; p += (size_t)NKVD * HID * 2;
  u16* wot   = (u16*)p; p += (size_t)2944 * NQ * 2;   // 23 N-tiles * 128 rows, padded
  u16* qbuf  = (u16*)p; p += (size_t)NH * S_LEN * HD * 2;
  u16* kbuf  = (u16*)p; p += (size_t)NKV * S_LEN * HD * 2;
  u16* vtbuf = (u16*)p; p += (size_t)NKV * HD * S_LEN * 2;
  u16* abuf  = (u16*)p; p += (size_t)S_LEN * NQ * 2;

  k_convert<<<(S_LEN * HID / 4 + 255) / 256, 256, 0, stream>>>(hs, hsb, S_LEN * HID / 4);
  k_transpose<<<dim3(NQ / 32, HID / 32), dim3(32, 8), 0, stream>>>(wq, wqt, HID, NQ);
  k_transpose<<<dim3(NKVD / 32, HID / 32), dim3(32, 8), 0, stream>>>(wk, wkt, HID, NKVD);
  k_transpose<<<dim3(NKVD / 32, HID / 32), dim3(32, 8), 0, stream>>>(wv, wvt, HID, NKVD);
  k_transpose<<<dim3(HID / 32, NQ / 32), dim3(32, 8), 0, stream>>>(wo, wot, NQ, HID);
  k_gemm_qkv<<<(NQ + 2 * NKVD) / 128 * (S_LEN / 128), 256, 0, stream>>>(
      hsb, wqt, wkt, wvt, bq, bk, bv, cosb, sinb, qbuf, kbuf, vtbuf);
  k_attn<<<dim3(S_LEN / 64, NH), 256, 0, stream>>>(qbuf, kbuf, vtbuf, sinks, abuf);
  k_gemm_out<<<23 * 16, 256, 0, stream>>>(abuf, wot, bo, out);
}